// Round 17
// baseline (2135.349 us; speedup 1.0000x reference)
//
#include <hip/hip_runtime.h>

// ---------- types ----------
typedef short short8 __attribute__((ext_vector_type(8)));   // 8 bf16 in 4 VGPRs
typedef float f32x4 __attribute__((ext_vector_type(4)));    // MFMA accumulator

#define N_USERS 4096
#define T_STEPS 64
#define SKEP 768
#define HDIM 256
#define KROLE 64

// ---------- helpers ----------
__device__ __forceinline__ unsigned short f2bfs(float f) {
  unsigned int u = __builtin_bit_cast(unsigned int, f);
  u += 0x7fffu + ((u >> 16) & 1u);          // round-to-nearest-even
  return (unsigned short)(u >> 16);
}
__device__ __forceinline__ float bf2f(unsigned short b) {
  unsigned int u = ((unsigned int)b) << 16;
  return __builtin_bit_cast(float, u);
}
__device__ __forceinline__ short8 pack8(float4 a, float4 b) {
  short8 o;
  o[0] = (short)f2bfs(a.x); o[1] = (short)f2bfs(a.y);
  o[2] = (short)f2bfs(a.z); o[3] = (short)f2bfs(a.w);
  o[4] = (short)f2bfs(b.x); o[5] = (short)f2bfs(b.y);
  o[6] = (short)f2bfs(b.z); o[7] = (short)f2bfs(b.w);
  return o;
}
__device__ __forceinline__ float sigm(float x) { return 1.0f / (1.0f + __expf(-x)); }
__device__ __forceinline__ float tanh_(float x) { return 1.0f - 2.0f / (1.0f + __expf(2.0f * x)); }

// async global->LDS, 16B/lane, linear dest (wave-uniform base + lane*16)
__device__ __forceinline__ void gload16(const void* g, void* l) {
  __builtin_amdgcn_global_load_lds(
      (const __attribute__((address_space(1))) unsigned int*)g,
      (__attribute__((address_space(3))) unsigned int*)l, 16, 0, 0);
}

// ---------- k_hist: length histogram -> cntGT[t] = #users with len > t ----------
__global__ __launch_bounds__(256) void k_hist(
    const int* __restrict__ lengths, int* __restrict__ cntGT)
{
  __shared__ int hist[65];
  const int tid = threadIdx.x;
  if (tid < 65) hist[tid] = 0;
  __syncthreads();
  for (int i = tid; i < N_USERS; i += 256) atomicAdd(&hist[lengths[i]], 1);
  __syncthreads();
  if (tid == 0) {
    int acc = 0;
    cntGT[64] = 0;
    for (int l = 64; l >= 1; --l) { acc += hist[l]; cntGT[l - 1] = acc; }
  }
}

// ---------- k_scatter: stable descending counting-sort scatter ----------
__global__ __launch_bounds__(64) void k_scatter(
    const int* __restrict__ lengths, const int* __restrict__ cntGT,
    int* __restrict__ perm)
{
  const int l = blockIdx.x + 1;     // 1..64
  const int lane = threadIdx.x;
  int base = cntGT[l];
  for (int c = 0; c < N_USERS; c += 64) {
    int u = c + lane;
    bool m = (lengths[u] == l);
    unsigned long long mask = __ballot(m);
    int rank = __popcll(mask & ((1ull << lane) - 1ull));
    if (m) perm[base + rank] = u;
    base += __popcll(mask);
  }
}

// ---------- k_prep: wcat (gate-permuted [Whh|Wih]), wcatX (bigx B image), bias ----------
__global__ __launch_bounds__(256) void k_prep(
    const float* __restrict__ Wih, const float* __restrict__ Whh,
    const float* __restrict__ bih, const float* __restrict__ bhh,
    unsigned short* __restrict__ wcat, unsigned short* __restrict__ wcatX,
    float* __restrict__ bias)
{
  int c = blockIdx.x;
  int gi = (c >> 4) & 3;
  int u = ((c >> 6) << 4) | (c & 15);
  int orig = gi * HDIM + u;
  for (int k = threadIdx.x; k < 1024; k += 256) {
    float w = (k < HDIM) ? Whh[(size_t)orig * HDIM + k]
                         : Wih[(size_t)orig * SKEP + (k - HDIM)];
    wcat[(size_t)c * 1024 + k] = f2bfs(w);
  }
  const int NtX = c >> 7, rrX = c & 127;
  for (int kcol = threadIdx.x; kcol < SKEP; kcol += 256) {
    int kt = kcol >> 6, kk = kcol & 63, cl = kk >> 3, e = kk & 7;
    int i = rrX * 8 + (cl ^ (rrX & 7));
    wcatX[(size_t)(NtX * 12 + kt) * 8192 + i * 8 + e] =
        f2bfs(Wih[(size_t)orig * SKEP + kcol]);
  }
  if (threadIdx.x == 0) bias[c] = bih[orig] + bhh[orig];
}

// ---------- k_bigx (r13 exact, best-measured 545us): X = hist[perm] @ W_ih^T ----------
__global__ __launch_bounds__(512) void k_bigx(
    const float* __restrict__ hist,
    const unsigned short* __restrict__ wcatX,
    const int* __restrict__ perm,
    const int* __restrict__ cntGT,
    unsigned short* __restrict__ X)
{
  __shared__ __align__(16) unsigned char smem[65536];
  unsigned char* const A0 = smem;
  unsigned char* const B0 = smem + 16384;
  unsigned char* const A1 = smem + 32768;
  unsigned char* const B1 = smem + 49152;

  const int tid = threadIdx.x;
  const int lane = tid & 63;
  const int wid = tid >> 6;
  const int wr = wid >> 1;
  const int wc = wid & 1;
  const int lr = lane & 15;
  const int lg = lane >> 4;

  const int d = blockIdx.x;
  const int x = d & 7;
  const int Nt = (d >> 3) & 7;
  const int g = ((d >> 6) << 3) | x;
  const int t = g >> 5;
  const int Mtu = g & 31;
  const int n0 = Mtu * 128;

  if ((Mtu << 7) >= cntGT[t]) return;         // no active (len>t) user in this tile

  f32x4 acc[2][4];
#pragma unroll
  for (int mi = 0; mi < 2; ++mi)
#pragma unroll
    for (int nj = 0; nj < 4; ++nj) acc[mi][nj] = f32x4{0.f, 0.f, 0.f, 0.f};

  const int rr = tid >> 3;
  const int cl = (tid & 7) ^ (rr & 7);
  const int u0 = perm[n0 + rr];
  const int u1 = perm[n0 + rr + 64];
  const size_t hA0 = ((size_t)u0 * T_STEPS + t) * SKEP + (size_t)cl * 8;
  const size_t hA1 = ((size_t)u1 * T_STEPS + t) * SKEP + (size_t)cl * 8;
  const int dst0 = tid * 16, dst1 = tid * 16 + 8192;

  {
    const unsigned short* img = wcatX + (size_t)(Nt * 12) * 8192;
    gload16(img + (size_t)tid * 8, B0 + wid * 1024);
    gload16(img + (size_t)(tid + 512) * 8, B0 + 8192 + wid * 1024);
    const float* p0 = hist + hA0;
    const float* p1 = hist + hA1;
    float4 f00 = *(const float4*)p0, f01 = *(const float4*)(p0 + 4);
    float4 f10 = *(const float4*)p1, f11 = *(const float4*)(p1 + 4);
    *(short8*)(A0 + dst0) = pack8(f00, f01);
    *(short8*)(A0 + dst1) = pack8(f10, f11);
  }
  __syncthreads();

  for (int kt = 0; kt < 12; ++kt) {
    unsigned char* curA = (kt & 1) ? A1 : A0;
    unsigned char* curB = (kt & 1) ? B1 : B0;
    unsigned char* nxtA = (kt & 1) ? A0 : A1;
    unsigned char* nxtB = (kt & 1) ? B0 : B1;
    const int kn = kt + 1;
    const bool have = (kn < 12);

    float4 f00, f01, f10, f11;
    if (have) {
      const unsigned short* img = wcatX + (size_t)(Nt * 12 + kn) * 8192;
      gload16(img + (size_t)tid * 8, nxtB + wid * 1024);
      gload16(img + (size_t)(tid + 512) * 8, nxtB + 8192 + wid * 1024);
      const float* p0 = hist + hA0 + (size_t)kn * 64;
      const float* p1 = hist + hA1 + (size_t)kn * 64;
      f00 = *(const float4*)p0; f01 = *(const float4*)(p0 + 4);
      f10 = *(const float4*)p1; f11 = *(const float4*)(p1 + 4);
    }

#pragma unroll
    for (int ks = 0; ks < 2; ++ks) {
      short8 av[2], bv[4];
#pragma unroll
      for (int mi = 0; mi < 2; ++mi) {
        int r = wr * 32 + mi * 16 + lr;
        int ph = (ks * 4 + lg) ^ (r & 7);
        av[mi] = *(const short8*)(curA + r * 128 + ph * 16);
      }
#pragma unroll
      for (int nj = 0; nj < 4; ++nj) {
        int r = wc * 64 + nj * 16 + lr;
        int ph = (ks * 4 + lg) ^ (r & 7);
        bv[nj] = *(const short8*)(curB + r * 128 + ph * 16);
      }
#pragma unroll
      for (int mi = 0; mi < 2; ++mi)
#pragma unroll
        for (int nj = 0; nj < 4; ++nj)
          acc[mi][nj] = __builtin_amdgcn_mfma_f32_16x16x32_bf16(av[mi], bv[nj], acc[mi][nj], 0, 0, 0);
    }

    if (have) {
      *(short8*)(nxtA + dst0) = pack8(f00, f01);
      *(short8*)(nxtA + dst1) = pack8(f10, f11);
    }
    __syncthreads();
  }

  unsigned short tmp[32];
#pragma unroll
  for (int mi = 0; mi < 2; ++mi)
#pragma unroll
    for (int nj = 0; nj < 4; ++nj)
#pragma unroll
      for (int q = 0; q < 4; ++q)
        tmp[mi * 16 + nj * 4 + q] = f2bfs(acc[mi][nj][q]);
  const int slab = t * 256 + (Mtu * 4 + wr) * 2 + (Nt >> 2);
  const int tidc = ((Nt * 2 + wc) & 7) * 64 + lg * 16 + lr;
  const size_t base = ((size_t)slab * 512 + tidc) * 32;
#pragma unroll
  for (int j2 = 0; j2 < 4; ++j2)
    *(short8*)(X + base + j2 * 8) = *(const short8*)(tmp + j2 * 8);
}

// ---------- k_lstm: single-block-per-user-group, zero inter-block sync ----------
// 128 blocks x 1024 threads (16 waves). Block owns 32 sorted users x ALL 1024
// gate-cols -> h lives entirely in 16KB LDS; no fabric traffic in the loop.
// FIX vs r16: X per-t stride is 256 slabs x 16384 elems = 4194304 (was 131072).
__global__ __launch_bounds__(1024) void k_lstm(
    const unsigned short* __restrict__ X,
    unsigned short* __restrict__ hfin,
    const unsigned short* __restrict__ wcat,
    const float* __restrict__ bias,
    const int* __restrict__ lengths,
    const int* __restrict__ perm)
{
  __shared__ __align__(16) unsigned char hl[16384];   // h [32 users][256 k] swizzled

  const int tid = threadIdx.x;
  const int lane = tid & 63;
  const int w = tid >> 6;          // 0..15
  const int lr = lane & 15, lg = lane >> 4;
  const int gg = blockIdx.x;       // 0..127
  const int n0 = gg * 32;

  // ---- W_hh fragments into registers (held entire kernel) ----
  short8 Breg[32];
#pragma unroll
  for (int nj = 0; nj < 4; ++nj) {
    const unsigned short* wp =
        wcat + (size_t)(w * 64 + nj * 16 + lr) * 1024 + lg * 8;
#pragma unroll
    for (int ks = 0; ks < 8; ++ks)
      Breg[nj * 8 + ks] = *(const short8*)(wp + ks * 32);
  }

  float bs[4];
#pragma unroll
  for (int nj = 0; nj < 4; ++nj)
    bs[nj] = bias[w * 64 + nj * 16 + lr];
  int pu[2][4], len[2][4];
#pragma unroll
  for (int mi = 0; mi < 2; ++mi)
#pragma unroll
    for (int q = 0; q < 4; ++q) {
      pu[mi][q] = perm[n0 + mi * 16 + lg * 4 + q];
      len[mi][q] = lengths[pu[mi][q]];
    }
  const int te = lengths[perm[n0]];   // block max length (descending sort)

  const int unitg = w * 16 + lr;      // this thread's unit (0..255)
  const int uchunk = unitg >> 3;
  const int ulow = (unitg & 7) * 2;

  for (int i = tid; i < 4096; i += 1024) ((unsigned int*)hl)[i] = 0;
  float c8[2][4] = {{0.f, 0.f, 0.f, 0.f}, {0.f, 0.f, 0.f, 0.f}};
  unsigned short hp8[2][4] = {{0, 0, 0, 0}, {0, 0, 0, 0}};

  // X chunk address base: same layout as pair-split (b = gg*2 + (w>>3), tid_old)
  const size_t xoff = ((size_t)(gg * 2 + (w >> 3)) * 512 + (w & 7) * 64 + lane) * 32;

  // X for step 0 (latency hidden under Breg loads + zero-init)
  short8 xc0, xc1, xc2, xc3;
  {
    const unsigned short* xp = X + xoff;
    xc0 = *(const short8*)(xp);
    xc1 = *(const short8*)(xp + 8);
    xc2 = *(const short8*)(xp + 16);
    xc3 = *(const short8*)(xp + 24);
  }
  __syncthreads();

#pragma unroll 1
  for (int t = 0; t < te; ++t) {
    // prefetch X for step t+1 (hides HBM latency under GEMM + epilogue)
    const int tn = (t + 1 < T_STEPS) ? (t + 1) : t;
    const unsigned short* xpn = X + (size_t)tn * 4194304ull + xoff;
    short8 xn0 = *(const short8*)(xpn);
    short8 xn1 = *(const short8*)(xpn + 8);
    short8 xn2 = *(const short8*)(xpn + 16);
    short8 xn3 = *(const short8*)(xpn + 24);

    // ---- GEMM: gates = h @ W_hh^T (W in regs, h frags from LDS) ----
    f32x4 acc[2][4];
#pragma unroll
    for (int mi = 0; mi < 2; ++mi)
#pragma unroll
      for (int nj = 0; nj < 4; ++nj) acc[mi][nj] = f32x4{0.f, 0.f, 0.f, 0.f};

#pragma unroll
    for (int ks = 0; ks < 8; ++ks) {
      const int ch = ks * 4 + lg;
      short8 av0 = *(const short8*)(hl + lr * 512 + ((ch ^ (lr & 7)) << 4));
      short8 av1 = *(const short8*)(hl + (16 + lr) * 512 + ((ch ^ (lr & 7)) << 4));
#pragma unroll
      for (int nj = 0; nj < 4; ++nj) {
        acc[0][nj] = __builtin_amdgcn_mfma_f32_16x16x32_bf16(av0, Breg[nj * 8 + ks], acc[0][nj], 0, 0, 0);
        acc[1][nj] = __builtin_amdgcn_mfma_f32_16x16x32_bf16(av1, Breg[nj * 8 + ks], acc[1][nj], 0, 0, 0);
      }
    }
    __syncthreads();   // all frag reads done before h overwrite

    // ---- cell update; h -> LDS (local, no global traffic) ----
#pragma unroll
    for (int mi = 0; mi < 2; ++mi) {
      const short8 xa = (mi == 0) ? xc0 : xc2;
      const short8 xb = (mi == 0) ? xc1 : xc3;
#pragma unroll
      for (int q = 0; q < 4; ++q) {
        float gi_ = sigm(acc[mi][0][q] + bf2f((unsigned short)xa[q])     + bs[0]);
        float gf_ = sigm(acc[mi][1][q] + bf2f((unsigned short)xa[4 + q]) + bs[1]);
        float gg_ = tanh_(acc[mi][2][q] + bf2f((unsigned short)xb[q])    + bs[2]);
        float go_ = sigm(acc[mi][3][q] + bf2f((unsigned short)xb[4 + q]) + bs[3]);
        if (t < len[mi][q]) {
          float cn = gf_ * c8[mi][q] + gi_ * gg_;
          c8[mi][q] = cn;
          hp8[mi][q] = f2bfs(go_ * tanh_(cn));
        }
        int us = mi * 16 + lg * 4 + q;
        *(unsigned short*)(hl + us * 512 + ((uchunk ^ (us & 7)) << 4) + ulow) = hp8[mi][q];
      }
    }
    __syncthreads();   // h writes visible for next step's frag reads

    xc0 = xn0; xc1 = xn1; xc2 = xn2; xc3 = xn3;
  }

  // final h -> global, scattered back to ORIGINAL user order
#pragma unroll
  for (int mi = 0; mi < 2; ++mi)
#pragma unroll
    for (int q = 0; q < 4; ++q)
      hfin[(size_t)pu[mi][q] * HDIM + unitg] = hp8[mi][q];
}

// ---------- Phase C1: s[n] = dot(cc[cid[n]], uv[n]) / sqrt(H) ----------
__global__ __launch_bounds__(256) void k_scores(
    const float* __restrict__ uv, const float* __restrict__ cc,
    const int* __restrict__ cid, float* __restrict__ s)
{
  int n = blockIdx.x * 4 + (threadIdx.x >> 6);
  int lane = threadIdx.x & 63;
  float4 a = *(const float4*)(uv + (size_t)n * HDIM + lane * 4);
  float4 b = *(const float4*)(cc + (size_t)cid[n] * HDIM + lane * 4);
  float dd = a.x * b.x + a.y * b.y + a.z * b.z + a.w * b.w;
  for (int off = 32; off; off >>= 1) dd += __shfl_down(dd, off);
  if (lane == 0) s[n] = dd * 0.0625f;   // 1/sqrt(256)
}

// ---------- Phase C2: segment softmax + role_senti ----------
__global__ __launch_bounds__(256) void k_role(
    const float* __restrict__ s, const int* __restrict__ cid,
    const unsigned short* __restrict__ hn, float* __restrict__ rs)
{
  __shared__ float sv[N_USERS];
  __shared__ int cv[N_USERS];
  __shared__ float red[256];
  const int k = blockIdx.x, tid = threadIdx.x;
  for (int i = tid; i < N_USERS; i += 256) { sv[i] = s[i]; cv[i] = cid[i]; }
  __syncthreads();
  float m = -3.4e38f;
  for (int i = tid; i < N_USERS; i += 256) if (cv[i] == k) m = fmaxf(m, sv[i]);
  red[tid] = m; __syncthreads();
  for (int st = 128; st; st >>= 1) { if (tid < st) red[tid] = fmaxf(red[tid], red[tid + st]); __syncthreads(); }
  const float smax = red[0];
  __syncthreads();
  float sum = 0.f;
  for (int i = tid; i < N_USERS; i += 256)
    if (cv[i] == k) { float e = __expf(sv[i] - smax); sv[i] = e; sum += e; }
  red[tid] = sum; __syncthreads();
  for (int st = 128; st; st >>= 1) { if (tid < st) red[tid] += red[tid + st]; __syncthreads(); }
  const float den = red[0];
  __syncthreads();
  float a = 0.f;
  for (int i = 0; i < N_USERS; ++i)
    if (cv[i] == k) a += sv[i] * bf2f(hn[(size_t)i * HDIM + tid]);
  rs[(size_t)k * HDIM + tid] = a / den;
}

// ---------- k_qkv: Q/K/V projections, one (mat,head,role,dim) task per thread ----------
__global__ __launch_bounds__(256) void k_qkv(
    const float* __restrict__ rs,
    const float* __restrict__ Wq, const float* __restrict__ bq,
    const float* __restrict__ Wk, const float* __restrict__ bk,
    const float* __restrict__ Wv, const float* __restrict__ bv,
    float* __restrict__ qkvg)
{
  const int id = blockIdx.x * 256 + threadIdx.x;
  const int m2 = id >> 14;
  const int hr = (id >> 5) & 511;
  const int dd2 = id & 31;
  const int head = hr >> 6, r = hr & 63;
  const int wrow = head * 32 + dd2;
  const float* W = (m2 == 0) ? Wq : (m2 == 1) ? Wk : Wv;
  const float* B = (m2 == 0) ? bq : (m2 == 1) ? bk : bv;
  const float* x = rs + (size_t)r * HDIM;
  const float* w = W + (size_t)wrow * HDIM;
  float acc = B[wrow];
#pragma unroll 4
  for (int j4 = 0; j4 < 64; ++j4) {
    float4 xv = *(const float4*)(x + j4 * 4);
    float4 wv = *(const float4*)(w + j4 * 4);
    acc += xv.x * wv.x;
    acc += xv.y * wv.y;
    acc += xv.z * wv.z;
    acc += xv.w * wv.w;
  }
  qkvg[(size_t)(m2 * 512 + hr) * 32 + dd2] = acc;
}

// ---------- Phase D1: per-head attention over roles (q/k/v precomputed) ----------
__global__ __launch_bounds__(256) void k_mha(
    const float* __restrict__ qkvg,
    float* __restrict__ attout)
{
  __shared__ float q[64][32], kk[64][32], v[64][32];
  __shared__ float att[64][64];
  const int h = blockIdx.x, tid = threadIdx.x;
  for (int i = tid; i < 2048; i += 256) {
    int r = i >> 5, dd2 = i & 31;
    q[r][dd2]  = qkvg[(size_t)(0 * 512 + h * 64 + r) * 32 + dd2];
    kk[r][dd2] = qkvg[(size_t)(1 * 512 + h * 64 + r) * 32 + dd2];
    v[r][dd2]  = qkvg[(size_t)(2 * 512 + h * 64 + r) * 32 + dd2];
  }
  __syncthreads();
  for (int idx = tid; idx < 4096; idx += 256) {
    int qr = idx >> 6, kr = idx & 63;
    float sc = 0.f;
    for (int dd2 = 0; dd2 < 32; ++dd2) sc += q[qr][dd2] * kk[kr][dd2];
    att[qr][kr] = sc * 0.17677669529663687f;   // 1/sqrt(32)
  }
  __syncthreads();
  if (tid < 64) {
    float m = -3.4e38f;
    for (int j = 0; j < 64; ++j) m = fmaxf(m, att[tid][j]);
    float sum = 0.f;
    for (int j = 0; j < 64; ++j) { float e = __expf(att[tid][j] - m); att[tid][j] = e; sum += e; }
    float inv = 1.f / sum;
    for (int j = 0; j < 64; ++j) att[tid][j] *= inv;
  }
  __syncthreads();
  for (int idx = tid; idx < 2048; idx += 256) {
    int r = idx >> 5, dd2 = idx & 31;
    float o = 0.f;
    for (int kr = 0; kr < 64; ++kr) o += att[r][kr] * v[kr][dd2];
    attout[(size_t)r * HDIM + h * 32 + dd2] = o;
  }
}

// ---------- Phase D2: mean over roles + Wo projection ----------
__global__ __launch_bounds__(256) void k_out(
    const float* __restrict__ attout, const float* __restrict__ Wo,
    const float* __restrict__ bo, float* __restrict__ out)
{
  __shared__ float m_s[256];
  const int tid = threadIdx.x;
  float mm = 0.f;
  for (int r = 0; r < 64; ++r) mm += attout[(size_t)r * HDIM + tid];
  m_s[tid] = mm * (1.0f / 64.0f);
  __syncthreads();
  float a = bo[tid];
  const float* w = Wo + (size_t)tid * HDIM;
#pragma unroll 4
  for (int j4 = 0; j4 < 64; ++j4) {
    float4 wv = *(const float4*)(w + j4 * 4);
    a += m_s[j4 * 4 + 0] * wv.x;
    a += m_s[j4 * 4 + 1] * wv.y;
    a += m_s[j4 * 4 + 2] * wv.z;
    a += m_s[j4 * 4 + 3] * wv.w;
  }
  out[tid] = a;
}

extern "C" void kernel_launch(void* const* d_in, const int* in_sizes, int n_in,
                              void* d_out, int out_size, void* d_ws, size_t ws_size,
                              hipStream_t stream) {
  const float* hist = (const float*)d_in[0];
  const float* uv   = (const float*)d_in[1];
  const float* cc   = (const float*)d_in[2];
  const float* Wih  = (const float*)d_in[3];
  const float* Whh  = (const float*)d_in[4];
  const float* bih  = (const float*)d_in[5];
  const float* bhh  = (const float*)d_in[6];
  const float* Wq   = (const float*)d_in[7];
  const float* bq   = (const float*)d_in[8];
  const float* Wk   = (const float*)d_in[9];
  const float* bk   = (const float*)d_in[10];
  const float* Wv   = (const float*)d_in[11];
  const float* bv   = (const float*)d_in[12];
  const float* Wo   = (const float*)d_in[13];
  const float* bo   = (const float*)d_in[14];
  const int* lengths = (const int*)d_in[15];
  const int* cid     = (const int*)d_in[16];
  float* out = (float*)d_out;

  unsigned char* ws = (unsigned char*)d_ws;
  unsigned short* hfin  = (unsigned short*)(ws);                      // 2 MB
  int* perm   = (int*)   (ws + (6ull << 20) + 16384);                 // 16 KB
  int* cntGT  = (int*)   (ws + (6ull << 20) + 32768);                 // 260 B
  float* bias   = (float*)(ws + (6ull << 20) + 65536);                // 4 KB
  float* sbuf   = (float*)(ws + (6ull << 20) + 73728);                // 16 KB
  float* rs     = (float*)(ws + (6ull << 20) + 98304);                // 64 KB
  float* attout = (float*)(ws + (6ull << 20) + 163840);               // 64 KB
  float* qkvg   = (float*)(ws + (7ull << 20));                        // 192 KB
  unsigned short* wcat  = (unsigned short*)(ws + (8ull << 20));       // 2 MB
  unsigned short* wcatX = (unsigned short*)(ws + (10ull << 20));      // 1.5 MB
  unsigned short* Xbuf  = (unsigned short*)(ws + (16ull << 20));      // 512 MB
  const size_t need = (16ull << 20) + (size_t)N_USERS * T_STEPS * 1024 * 2;
  if (ws_size < need) return;

  k_hist<<<1, 256, 0, stream>>>(lengths, cntGT);
  k_scatter<<<64, 64, 0, stream>>>(lengths, cntGT, perm);
  k_prep<<<1024, 256, 0, stream>>>(Wih, Whh, bih, bhh, wcat, wcatX, bias);
  k_bigx<<<16384, 512, 0, stream>>>(hist, wcatX, perm, cntGT, Xbuf);
  k_lstm<<<128, 1024, 0, stream>>>(Xbuf, hfin, wcat, bias, lengths, perm);

  k_scores<<<1024, 256, 0, stream>>>(uv, cc, cid, sbuf);
  k_role<<<64, 256, 0, stream>>>(sbuf, cid, hfin, rs);
  k_qkv<<<192, 256, 0, stream>>>(rs, Wq, bq, Wk, bk, Wv, bv, qkvg);
  k_mha<<<8, 256, 0, stream>>>(qkvg, attout);
  k_out<<<1, 256, 0, stream>>>(attout, Wo, bo, out);
}

// Round 18
// 980.357 us; speedup vs baseline: 2.1781x; 2.1781x over previous
//
#include <hip/hip_runtime.h>

// ---------- types ----------
typedef short short8 __attribute__((ext_vector_type(8)));   // 8 bf16 in 4 VGPRs
typedef float f32x4 __attribute__((ext_vector_type(4)));    // MFMA accumulator

#define N_USERS 4096
#define T_STEPS 64
#define SKEP 768
#define HDIM 256
#define KROLE 64

// ---------- helpers ----------
__device__ __forceinline__ unsigned short f2bfs(float f) {
  unsigned int u = __builtin_bit_cast(unsigned int, f);
  u += 0x7fffu + ((u >> 16) & 1u);          // round-to-nearest-even
  return (unsigned short)(u >> 16);
}
__device__ __forceinline__ float bf2f(unsigned short b) {
  unsigned int u = ((unsigned int)b) << 16;
  return __builtin_bit_cast(float, u);
}
__device__ __forceinline__ short8 pack8(float4 a, float4 b) {
  short8 o;
  o[0] = (short)f2bfs(a.x); o[1] = (short)f2bfs(a.y);
  o[2] = (short)f2bfs(a.z); o[3] = (short)f2bfs(a.w);
  o[4] = (short)f2bfs(b.x); o[5] = (short)f2bfs(b.y);
  o[6] = (short)f2bfs(b.z); o[7] = (short)f2bfs(b.w);
  return o;
}
__device__ __forceinline__ float sigm(float x) { return 1.0f / (1.0f + __expf(-x)); }
__device__ __forceinline__ float tanh_(float x) { return 1.0f - 2.0f / (1.0f + __expf(2.0f * x)); }

// async global->LDS, 16B/lane, linear dest (wave-uniform base + lane*16)
__device__ __forceinline__ void gload16(const void* g, void* l) {
  __builtin_amdgcn_global_load_lds(
      (const __attribute__((address_space(1))) unsigned int*)g,
      (__attribute__((address_space(3))) unsigned int*)l, 16, 0, 0);
}

// coherence-point (sc0 sc1) 8B store: visible device-wide after vmcnt(0)
__device__ __forceinline__ void store_u64_coh(unsigned short* p, unsigned long long v) {
  asm volatile("global_store_dwordx2 %0, %1, off sc0 sc1" : : "v"(p), "v"(v) : "memory");
}

// ---------- k_hist: length histogram -> cntGT[t] = #users with len > t ----------
__global__ __launch_bounds__(256) void k_hist(
    const int* __restrict__ lengths, int* __restrict__ cntGT)
{
  __shared__ int hist[65];
  const int tid = threadIdx.x;
  if (tid < 65) hist[tid] = 0;
  __syncthreads();
  for (int i = tid; i < N_USERS; i += 256) atomicAdd(&hist[lengths[i]], 1);
  __syncthreads();
  if (tid == 0) {
    int acc = 0;
    cntGT[64] = 0;
    for (int l = 64; l >= 1; --l) { acc += hist[l]; cntGT[l - 1] = acc; }
  }
}

// ---------- k_scatter: stable descending counting-sort scatter (by length) ----------
__global__ __launch_bounds__(64) void k_scatter(
    const int* __restrict__ lengths, const int* __restrict__ cntGT,
    int* __restrict__ perm)
{
  const int l = blockIdx.x + 1;     // 1..64
  const int lane = threadIdx.x;
  int base = cntGT[l];
  for (int c = 0; c < N_USERS; c += 64) {
    int u = c + lane;
    bool m = (lengths[u] == l);
    unsigned long long mask = __ballot(m);
    int rank = __popcll(mask & ((1ull << lane) - 1ull));
    if (m) perm[base + rank] = u;
    base += __popcll(mask);
  }
}

// ---------- k_hist2: cid histogram -> cidoff[k] = start of role k ----------
__global__ __launch_bounds__(256) void k_hist2(
    const int* __restrict__ cid, int* __restrict__ cidoff)
{
  __shared__ int hist[64];
  const int tid = threadIdx.x;
  if (tid < 64) hist[tid] = 0;
  __syncthreads();
  for (int i = tid; i < N_USERS; i += 256) atomicAdd(&hist[cid[i]], 1);
  __syncthreads();
  if (tid == 0) {
    int acc = 0;
    for (int k = 0; k < 64; ++k) { cidoff[k] = acc; acc += hist[k]; }
    cidoff[64] = acc;
  }
}

// ---------- k_scatter2: stable ascending scatter by cid -> clist ----------
__global__ __launch_bounds__(64) void k_scatter2(
    const int* __restrict__ cid, const int* __restrict__ cidoff,
    int* __restrict__ clist)
{
  const int k = blockIdx.x;         // 0..63
  const int lane = threadIdx.x;
  int base = cidoff[k];
  for (int c = 0; c < N_USERS; c += 64) {
    int u = c + lane;
    bool m = (cid[u] == k);
    unsigned long long mask = __ballot(m);
    int rank = __popcll(mask & ((1ull << lane) - 1ull));
    if (m) clist[base + rank] = u;
    base += __popcll(mask);
  }
}

// ---------- k_prep: wcat (gate-permuted [Whh|Wih]), wcatX (bigx B image), bias ----------
__global__ __launch_bounds__(256) void k_prep(
    const float* __restrict__ Wih, const float* __restrict__ Whh,
    const float* __restrict__ bih, const float* __restrict__ bhh,
    unsigned short* __restrict__ wcat, unsigned short* __restrict__ wcatX,
    float* __restrict__ bias)
{
  int c = blockIdx.x;
  int gi = (c >> 4) & 3;
  int u = ((c >> 6) << 4) | (c & 15);
  int orig = gi * HDIM + u;
  for (int k = threadIdx.x; k < 1024; k += 256) {
    float w = (k < HDIM) ? Whh[(size_t)orig * HDIM + k]
                         : Wih[(size_t)orig * SKEP + (k - HDIM)];
    wcat[(size_t)c * 1024 + k] = f2bfs(w);
  }
  const int NtX = c >> 7, rrX = c & 127;
  for (int kcol = threadIdx.x; kcol < SKEP; kcol += 256) {
    int kt = kcol >> 6, kk = kcol & 63, cl = kk >> 3, e = kk & 7;
    int i = rrX * 8 + (cl ^ (rrX & 7));
    wcatX[(size_t)(NtX * 12 + kt) * 8192 + i * 8 + e] =
        f2bfs(Wih[(size_t)orig * SKEP + kcol]);
  }
  if (threadIdx.x == 0) bias[c] = bih[orig] + bhh[orig];
}

// ---------- k_bigx (r14): X = hist[perm] @ W_ih^T, length-skip + deep pipeline ----------
__global__ __launch_bounds__(512) void k_bigx(
    const float* __restrict__ hist,
    const unsigned short* __restrict__ wcatX,
    const int* __restrict__ perm,
    const int* __restrict__ cntGT,
    unsigned short* __restrict__ X)
{
  __shared__ __align__(16) unsigned char smem[81920];   // A:2x16K + B:3x16K
  unsigned char* const Ab0 = smem;
  unsigned char* const Ab1 = smem + 16384;
  unsigned char* const Bb0 = smem + 32768;
  unsigned char* const Bb1 = smem + 49152;
  unsigned char* const Bb2 = smem + 65536;
  unsigned char* const Ab[2] = {Ab0, Ab1};
  unsigned char* const Bb[3] = {Bb0, Bb1, Bb2};

  const int tid = threadIdx.x;
  const int lane = tid & 63;
  const int wid = tid >> 6;
  const int wr = wid >> 1;
  const int wc = wid & 1;
  const int lr = lane & 15;
  const int lg = lane >> 4;

  const int d = blockIdx.x;
  const int x = d & 7;
  const int Nt = (d >> 3) & 7;
  const int g = ((d >> 6) << 3) | x;
  const int t = g >> 5;
  const int Mtu = g & 31;
  const int n0 = Mtu * 128;

  if ((Mtu << 7) >= cntGT[t]) return;         // no active (len>t) user in this tile

  f32x4 acc[2][4];
#pragma unroll
  for (int mi = 0; mi < 2; ++mi)
#pragma unroll
    for (int nj = 0; nj < 4; ++nj) acc[mi][nj] = f32x4{0.f, 0.f, 0.f, 0.f};

  const int rr = tid >> 3;
  const int cl = (tid & 7) ^ (rr & 7);
  const int u0 = perm[n0 + rr];
  const int u1 = perm[n0 + rr + 64];
  const size_t hA0 = ((size_t)u0 * T_STEPS + t) * SKEP + (size_t)cl * 8;
  const size_t hA1 = ((size_t)u1 * T_STEPS + t) * SKEP + (size_t)cl * 8;
  const int dst0 = tid * 16, dst1 = tid * 16 + 8192;

  const unsigned short* img = wcatX + (size_t)(Nt * 12) * 8192;

  float4 fa[3][4];

  // prologue: issue B(0),B(1); A(0..2); pack A(0)
  gload16(img + (size_t)tid * 8,          Bb0 + wid * 1024);
  gload16(img + (size_t)(tid + 512) * 8,  Bb0 + 8192 + wid * 1024);
  gload16(img + 8192 + (size_t)tid * 8,         Bb1 + wid * 1024);
  gload16(img + 8192 + (size_t)(tid + 512) * 8, Bb1 + 8192 + wid * 1024);
#pragma unroll
  for (int p = 0; p < 3; ++p) {
    const float* p0 = hist + hA0 + (size_t)p * 64;
    const float* p1 = hist + hA1 + (size_t)p * 64;
    fa[p][0] = *(const float4*)p0; fa[p][1] = *(const float4*)(p0 + 4);
    fa[p][2] = *(const float4*)p1; fa[p][3] = *(const float4*)(p1 + 4);
  }
  *(short8*)(Ab0 + dst0) = pack8(fa[0][0], fa[0][1]);
  *(short8*)(Ab0 + dst1) = pack8(fa[0][2], fa[0][3]);
  asm volatile("s_waitcnt vmcnt(8) lgkmcnt(0)" ::: "memory");
  __builtin_amdgcn_s_barrier();

#pragma unroll
  for (int kt = 0; kt < 12; ++kt) {
    if (kt + 2 < 12) {
      const unsigned short* ik = img + (size_t)(kt + 2) * 8192;
      gload16(ik + (size_t)tid * 8,         Bb[(kt + 2) % 3] + wid * 1024);
      gload16(ik + (size_t)(tid + 512) * 8, Bb[(kt + 2) % 3] + 8192 + wid * 1024);
    }
    if (kt + 1 < 12) {
      *(short8*)(Ab[(kt + 1) & 1] + dst0) = pack8(fa[(kt + 1) % 3][0], fa[(kt + 1) % 3][1]);
      *(short8*)(Ab[(kt + 1) & 1] + dst1) = pack8(fa[(kt + 1) % 3][2], fa[(kt + 1) % 3][3]);
    }
    if (kt + 3 < 12) {
      const float* p0 = hist + hA0 + (size_t)(kt + 3) * 64;
      const float* p1 = hist + hA1 + (size_t)(kt + 3) * 64;
      fa[(kt + 3) % 3][0] = *(const float4*)p0; fa[(kt + 3) % 3][1] = *(const float4*)(p0 + 4);
      fa[(kt + 3) % 3][2] = *(const float4*)p1; fa[(kt + 3) % 3][3] = *(const float4*)(p1 + 4);
    }

    unsigned char* curA = Ab[kt & 1];
    unsigned char* curB = Bb[kt % 3];
#pragma unroll
    for (int ks = 0; ks < 2; ++ks) {
      short8 av[2], bv[4];
#pragma unroll
      for (int mi = 0; mi < 2; ++mi) {
        int r = wr * 32 + mi * 16 + lr;
        int ph = (ks * 4 + lg) ^ (r & 7);
        av[mi] = *(const short8*)(curA + r * 128 + ph * 16);
      }
#pragma unroll
      for (int nj = 0; nj < 4; ++nj) {
        int r = wc * 64 + nj * 16 + lr;
        int ph = (ks * 4 + lg) ^ (r & 7);
        bv[nj] = *(const short8*)(curB + r * 128 + ph * 16);
      }
#pragma unroll
      for (int mi = 0; mi < 2; ++mi)
#pragma unroll
        for (int nj = 0; nj < 4; ++nj)
          acc[mi][nj] = __builtin_amdgcn_mfma_f32_16x16x32_bf16(av[mi], bv[nj], acc[mi][nj], 0, 0, 0);
    }

    if (kt < 11) {
      if (kt <= 8) {
        asm volatile("s_waitcnt vmcnt(10) lgkmcnt(0)" ::: "memory");
      } else if (kt == 9) {
        asm volatile("s_waitcnt vmcnt(6) lgkmcnt(0)" ::: "memory");
      } else {
        asm volatile("s_waitcnt vmcnt(0) lgkmcnt(0)" ::: "memory");
      }
      __builtin_amdgcn_s_barrier();
    }
  }

  // epilogue: one contiguous 64B chunk per thread (k_lstm layout)
  unsigned short tmp[32];
#pragma unroll
  for (int mi = 0; mi < 2; ++mi)
#pragma unroll
    for (int nj = 0; nj < 4; ++nj)
#pragma unroll
      for (int q = 0; q < 4; ++q)
        tmp[mi * 16 + nj * 4 + q] = f2bfs(acc[mi][nj][q]);
  const int slab = t * 256 + (Mtu * 4 + wr) * 2 + (Nt >> 2);
  const int tidc = ((Nt * 2 + wc) & 7) * 64 + lg * 16 + lr;
  const size_t base = ((size_t)slab * 512 + tidc) * 32;
#pragma unroll
  for (int j2 = 0; j2 < 4; ++j2)
    *(short8*)(X + base + j2 * 8) = *(const short8*)(tmp + j2 * 8);
}

// ---------- k_lstm (r12/r14): pair-split persistent, W_hh in registers ----------
__global__ __launch_bounds__(512) void k_lstm(
    const unsigned short* __restrict__ X,
    unsigned short* __restrict__ hfin,
    unsigned short* __restrict__ hx0,
    unsigned short* __restrict__ hx1,
    const unsigned short* __restrict__ wcat,
    const float* __restrict__ bias,
    const int* __restrict__ lengths,
    const int* __restrict__ perm,
    unsigned int* __restrict__ ctr)
{
  __shared__ __align__(16) unsigned char hl[16384];

  const int tid = threadIdx.x;
  const int lane = tid & 63;
  const int w = tid >> 6;
  const int lr = lane & 15, lg = lane >> 4;
  const int b = blockIdx.x;
  const int gg = b >> 1, half = b & 1;
  const int n0 = gg * 32;
  const int pb = b ^ 1;
  unsigned int* const cme = ctr + b * 16;
  unsigned int* const cpa = ctr + pb * 16;

  short8 Breg[32];
#pragma unroll
  for (int nj = 0; nj < 4; ++nj) {
    const unsigned short* wp =
        wcat + (size_t)(half * 512 + w * 64 + nj * 16 + lr) * 1024 + lg * 8;
#pragma unroll
    for (int ks = 0; ks < 8; ++ks)
      Breg[nj * 8 + ks] = *(const short8*)(wp + ks * 32);
  }

  float bs[4];
#pragma unroll
  for (int nj = 0; nj < 4; ++nj)
    bs[nj] = bias[half * 512 + w * 64 + nj * 16 + lr];
  int pu[2][4], len[2][4];
#pragma unroll
  for (int mi = 0; mi < 2; ++mi)
#pragma unroll
    for (int q = 0; q < 4; ++q) {
      pu[mi][q] = perm[n0 + mi * 16 + lg * 4 + q];
      len[mi][q] = lengths[pu[mi][q]];
    }
  const int te = lengths[perm[n0]];

  const int unitg = half * 128 + w * 16 + lr;
  const int uchunk = unitg >> 3;
  const int ulow = (unitg & 7) * 2;

  for (int i = tid; i < 4096; i += 512) ((unsigned int*)hl)[i] = 0;
  float c8[2][4] = {{0.f, 0.f, 0.f, 0.f}, {0.f, 0.f, 0.f, 0.f}};
  unsigned short hp8[2][4] = {{0, 0, 0, 0}, {0, 0, 0, 0}};

  short8 xc0, xc1, xc2, xc3;
  {
    const unsigned short* xp = X + ((size_t)b * 512 + tid) * 32;
    xc0 = *(const short8*)(xp);
    xc1 = *(const short8*)(xp + 8);
    xc2 = *(const short8*)(xp + 16);
    xc3 = *(const short8*)(xp + 24);
  }
  __syncthreads();

#pragma unroll 1
  for (int t = 0; t < te; ++t) {
    if (t > 0) {
      if (tid == 0) {
        while (__hip_atomic_load(cpa, __ATOMIC_RELAXED, __HIP_MEMORY_SCOPE_AGENT)
               < (unsigned)t)
          __builtin_amdgcn_s_sleep(1);
      }
      __syncthreads();
      const unsigned long long* hs = (const unsigned long long*)
          (((t & 1) ? hx0 : hx1) + (size_t)pb * 4096);
      unsigned long long a0 = __hip_atomic_load(hs + tid * 2,
                                  __ATOMIC_RELAXED, __HIP_MEMORY_SCOPE_AGENT);
      unsigned long long a1 = __hip_atomic_load(hs + tid * 2 + 1,
                                  __ATOMIC_RELAXED, __HIP_MEMORY_SCOPE_AGENT);
      const int ku = (1 - half) * 128 + (tid >> 2);
      const int kc = ku >> 3, kl = (ku & 7) * 2;
      const int ub = (tid & 3) * 8;
#pragma unroll
      for (int j = 0; j < 8; ++j) {
        unsigned short hv = (unsigned short)
            ((j < 4) ? (a0 >> (j * 16)) : (a1 >> ((j - 4) * 16)));
        int us = ub + j;
        *(unsigned short*)(hl + us * 512 + ((kc ^ (us & 7)) << 4) + kl) = hv;
      }
      __syncthreads();
    }

    const int tn = (t + 1 < T_STEPS) ? (t + 1) : t;
    const unsigned short* xpn = X + (((size_t)tn * 256 + b) * 512 + tid) * 32;
    short8 xn0 = *(const short8*)(xpn);
    short8 xn1 = *(const short8*)(xpn + 8);
    short8 xn2 = *(const short8*)(xpn + 16);
    short8 xn3 = *(const short8*)(xpn + 24);

    f32x4 acc[2][4];
#pragma unroll
    for (int mi = 0; mi < 2; ++mi)
#pragma unroll
      for (int nj = 0; nj < 4; ++nj) acc[mi][nj] = f32x4{0.f, 0.f, 0.f, 0.f};

#pragma unroll
    for (int ks = 0; ks < 8; ++ks) {
      const int ch = ks * 4 + lg;
      short8 av0 = *(const short8*)(hl + lr * 512 + ((ch ^ (lr & 7)) << 4));
      short8 av1 = *(const short8*)(hl + (16 + lr) * 512 + ((ch ^ (lr & 7)) << 4));
#pragma unroll
      for (int nj = 0; nj < 4; ++nj) {
        acc[0][nj] = __builtin_amdgcn_mfma_f32_16x16x32_bf16(av0, Breg[nj * 8 + ks], acc[0][nj], 0, 0, 0);
        acc[1][nj] = __builtin_amdgcn_mfma_f32_16x16x32_bf16(av1, Breg[nj * 8 + ks], acc[1][nj], 0, 0, 0);
      }
    }
    __syncthreads();

    unsigned short* hxo = ((t & 1) ? hx1 : hx0) + (size_t)b * 4096;
#pragma unroll
    for (int mi = 0; mi < 2; ++mi) {
      const short8 xa = (mi == 0) ? xc0 : xc2;
      const short8 xb = (mi == 0) ? xc1 : xc3;
#pragma unroll
      for (int q = 0; q < 4; ++q) {
        float gi_ = sigm(acc[mi][0][q] + bf2f((unsigned short)xa[q])     + bs[0]);
        float gf_ = sigm(acc[mi][1][q] + bf2f((unsigned short)xa[4 + q]) + bs[1]);
        float gg_ = tanh_(acc[mi][2][q] + bf2f((unsigned short)xb[q])    + bs[2]);
        float go_ = sigm(acc[mi][3][q] + bf2f((unsigned short)xb[4 + q]) + bs[3]);
        if (t < len[mi][q]) {
          float cn = gf_ * c8[mi][q] + gi_ * gg_;
          c8[mi][q] = cn;
          hp8[mi][q] = f2bfs(go_ * tanh_(cn));
        }
        int us = mi * 16 + lg * 4 + q;
        *(unsigned short*)(hl + us * 512 + ((uchunk ^ (us & 7)) << 4) + ulow) = hp8[mi][q];
      }
      unsigned long long pk =
          (unsigned long long)hp8[mi][0] | ((unsigned long long)hp8[mi][1] << 16) |
          ((unsigned long long)hp8[mi][2] << 32) | ((unsigned long long)hp8[mi][3] << 48);
      store_u64_coh(hxo + (w * 16 + lr) * 32 + mi * 16 + lg * 4, pk);
    }

    asm volatile("s_waitcnt vmcnt(0)" ::: "memory");
    __syncthreads();
    if (t < te - 1 && tid == 0)
      __hip_atomic_fetch_add(cme, 1u, __ATOMIC_RELAXED, __HIP_MEMORY_SCOPE_AGENT);

    xc0 = xn0; xc1 = xn1; xc2 = xn2; xc3 = xn3;
  }

#pragma unroll
  for (int mi = 0; mi < 2; ++mi)
#pragma unroll
    for (int q = 0; q < 4; ++q)
      hfin[(size_t)pu[mi][q] * HDIM + unitg] = hp8[mi][q];
}

// ---------- Phase C1: s[n] = dot(cc[cid[n]], uv[n]) / sqrt(H) ----------
__global__ __launch_bounds__(256) void k_scores(
    const float* __restrict__ uv, const float* __restrict__ cc,
    const int* __restrict__ cid, float* __restrict__ s)
{
  int n = blockIdx.x * 4 + (threadIdx.x >> 6);
  int lane = threadIdx.x & 63;
  float4 a = *(const float4*)(uv + (size_t)n * HDIM + lane * 4);
  float4 b = *(const float4*)(cc + (size_t)cid[n] * HDIM + lane * 4);
  float dd = a.x * b.x + a.y * b.y + a.z * b.z + a.w * b.w;
  for (int off = 32; off; off >>= 1) dd += __shfl_down(dd, off);
  if (lane == 0) s[n] = dd * 0.0625f;   // 1/sqrt(256)
}

// ---------- Phase C2: segment softmax + role_senti (cid-list weighted sum) ----------
__global__ __launch_bounds__(256) void k_role(
    const float* __restrict__ s, const int* __restrict__ cid,
    const unsigned short* __restrict__ hn,
    const int* __restrict__ cidoff, const int* __restrict__ clist,
    float* __restrict__ rs)
{
  __shared__ float sv[N_USERS];
  __shared__ int cv[N_USERS];
  __shared__ float red[256];
  const int k = blockIdx.x, tid = threadIdx.x;
  for (int i = tid; i < N_USERS; i += 256) { sv[i] = s[i]; cv[i] = cid[i]; }
  __syncthreads();
  float m = -3.4e38f;
  for (int i = tid; i < N_USERS; i += 256) if (cv[i] == k) m = fmaxf(m, sv[i]);
  red[tid] = m; __syncthreads();
  for (int st = 128; st; st >>= 1) { if (tid < st) red[tid] = fmaxf(red[tid], red[tid + st]); __syncthreads(); }
  const float smax = red[0];
  __syncthreads();
  float sum = 0.f;
  for (int i = tid; i < N_USERS; i += 256)
    if (cv[i] == k) { float e = __expf(sv[i] - smax); sv[i] = e; sum += e; }
  red[tid] = sum; __syncthreads();
  for (int st = 128; st; st >>= 1) { if (tid < st) red[tid] += red[tid + st]; __syncthreads(); }
  const float den = red[0];
  __syncthreads();
  // weighted h-sum over role members only (ascending user order == old serial order)
  const int st0 = cidoff[k], en0 = cidoff[k + 1];
  float a = 0.f;
  for (int j = st0; j < en0; ++j) {
    int u = clist[j];
    a += sv[u] * bf2f(hn[(size_t)u * HDIM + tid]);
  }
  rs[(size_t)k * HDIM + tid] = a / den;
}

// ---------- k_qkv: Q/K/V projections, one (mat,head,role,dim) task per thread ----------
__global__ __launch_bounds__(256) void k_qkv(
    const float* __restrict__ rs,
    const float* __restrict__ Wq, const float* __restrict__ bq,
    const float* __restrict__ Wk, const float* __restrict__ bk,
    const float* __restrict__ Wv, const float* __restrict__ bv,
    float* __restrict__ qkvg)
{
  const int id = blockIdx.x * 256 + threadIdx.x;
  const int m2 = id >> 14;
  const int hr = (id >> 5) & 511;
  const int dd2 = id & 31;
  const int head = hr >> 6, r = hr & 63;
  const int wrow = head * 32 + dd2;
  const float* W = (m2 == 0) ? Wq : (m2 == 1) ? Wk : Wv;
  const float* B = (m2 == 0) ? bq : (m2 == 1) ? bk : bv;
  const float* x = rs + (size_t)r * HDIM;
  const float* w = W + (size_t)wrow * HDIM;
  float acc = B[wrow];
#pragma unroll 4
  for (int j4 = 0; j4 < 64; ++j4) {
    float4 xv = *(const float4*)(x + j4 * 4);
    float4 wv = *(const float4*)(w + j4 * 4);
    acc += xv.x * wv.x;
    acc += xv.y * wv.y;
    acc += xv.z * wv.z;
    acc += xv.w * wv.w;
  }
  qkvg[(size_t)(m2 * 512 + hr) * 32 + dd2] = acc;
}

// ---------- Phase D1: per-head attention over roles (q/k/v precomputed) ----------
__global__ __launch_bounds__(256) void k_mha(
    const float* __restrict__ qkvg,
    float* __restrict__ attout)
{
  __shared__ float q[64][32], kk[64][32], v[64][32];
  __shared__ float att[64][64];
  const int h = blockIdx.x, tid = threadIdx.x;
  for (int i = tid; i < 2048; i += 256) {
    int r = i >> 5, dd2 = i & 31;
    q[r][dd2]  = qkvg[(size_t)(0 * 512 + h * 64 + r) * 32 + dd2];
    kk[r][dd2] = qkvg[(size_t)(1 * 512 + h * 64 + r) * 32 + dd2];
    v[r][dd2]  = qkvg[(size_t)(2 * 512 + h * 64 + r) * 32 + dd2];
  }
  __syncthreads();
  for (int idx = tid; idx < 4096; idx += 256) {
    int qr = idx >> 6, kr = idx & 63;
    float sc = 0.f;
    for (int dd2 = 0; dd2 < 32; ++dd2) sc += q[qr][dd2] * kk[kr][dd2];
    att[qr][kr] = sc * 0.17677669529663687f;   // 1/sqrt(32)
  }
  __syncthreads();
  if (tid < 64) {
    float m = -3.4e38f;
    for (int j = 0; j < 64; ++j) m = fmaxf(m, att[tid][j]);
    float sum = 0.f;
    for (int j = 0; j < 64; ++j) { float e = __expf(att[tid][j] - m); att[tid][j] = e; sum += e; }
    float inv = 1.f / sum;
    for (int j = 0; j < 64; ++j) att[tid][j] *= inv;
  }
  __syncthreads();
  for (int idx = tid; idx < 2048; idx += 256) {
    int r = idx >> 5, dd2 = idx & 31;
    float o = 0.f;
    for (int kr = 0; kr < 64; ++kr) o += att[r][kr] * v[kr][dd2];
    attout[(size_t)r * HDIM + h * 32 + dd2] = o;
  }
}

// ---------- Phase D2: mean over roles + Wo projection ----------
__global__ __launch_bounds__(256) void k_out(
    const float* __restrict__ attout, const float* __restrict__ Wo,
    const float* __restrict__ bo, float* __restrict__ out)
{
  __shared__ float m_s[256];
  const int tid = threadIdx.x;
  float mm = 0.f;
  for (int r = 0; r < 64; ++r) mm += attout[(size_t)r * HDIM + tid];
  m_s[tid] = mm * (1.0f / 64.0f);
  __syncthreads();
  float a = bo[tid];
  const float* w = Wo + (size_t)tid * HDIM;
#pragma unroll 4
  for (int j4 = 0; j4 < 64; ++j4) {
    float4 wv = *(const float4*)(w + j4 * 4);
    a += m_s[j4 * 4 + 0] * wv.x;
    a += m_s[j4 * 4 + 1] * wv.y;
    a += m_s[j4 * 4 + 2] * wv.z;
    a += m_s[j4 * 4 + 3] * wv.w;
  }
  out[tid] = a;
}

extern "C" void kernel_launch(void* const* d_in, const int* in_sizes, int n_in,
                              void* d_out, int out_size, void* d_ws, size_t ws_size,
                              hipStream_t stream) {
  const float* hist = (const float*)d_in[0];
  const float* uv   = (const float*)d_in[1];
  const float* cc   = (const float*)d_in[2];
  const float* Wih  = (const float*)d_in[3];
  const float* Whh  = (const float*)d_in[4];
  const float* bih  = (const float*)d_in[5];
  const float* bhh  = (const float*)d_in[6];
  const float* Wq   = (const float*)d_in[7];
  const float* bq   = (const float*)d_in[8];
  const float* Wk   = (const float*)d_in[9];
  const float* bk   = (const float*)d_in[10];
  const float* Wv   = (const float*)d_in[11];
  const float* bv   = (const float*)d_in[12];
  const float* Wo   = (const float*)d_in[13];
  const float* bo   = (const float*)d_in[14];
  const int* lengths = (const int*)d_in[15];
  const int* cid     = (const int*)d_in[16];
  float* out = (float*)d_out;

  unsigned char* ws = (unsigned char*)d_ws;
  unsigned short* hfin  = (unsigned short*)(ws);                      // 2 MB
  unsigned short* hx0   = (unsigned short*)(ws + (2ull << 20));       // 2 MB
  unsigned short* hx1   = (unsigned short*)(ws + (4ull << 20));       // 2 MB
  unsigned int*   ctr   = (unsigned int*)  (ws + (6ull << 20));       // 16 KB
  int* perm   = (int*)   (ws + (6ull << 20) + 16384);                 // 16 KB
  int* cntGT  = (int*)   (ws + (6ull << 20) + 32768);                 // 260 B
  int* cidoff = (int*)   (ws + (6ull << 20) + 33280);                 // 260 B
  int* clist  = (int*)   (ws + (6ull << 20) + 36864);                 // 16 KB
  float* bias   = (float*)(ws + (6ull << 20) + 65536);                // 4 KB
  float* sbuf   = (float*)(ws + (6ull << 20) + 73728);                // 16 KB
  float* rs     = (float*)(ws + (6ull << 20) + 98304);                // 64 KB
  float* attout = (float*)(ws + (6ull << 20) + 163840);               // 64 KB
  float* qkvg   = (float*)(ws + (7ull << 20));                        // 192 KB
  unsigned short* wcat  = (unsigned short*)(ws + (8ull << 20));       // 2 MB
  unsigned short* wcatX = (unsigned short*)(ws + (10ull << 20));      // 1.5 MB
  unsigned short* Xbuf  = (unsigned short*)(ws + (16ull << 20));      // 512 MB
  const size_t need = (16ull << 20) + (size_t)N_USERS * T_STEPS * 1024 * 2;
  if (ws_size < need) return;

  (void)hipMemsetAsync(ctr, 0, 16384, stream);

  k_hist<<<1, 256, 0, stream>>>(lengths, cntGT);
  k_scatter<<<64, 64, 0, stream>>>(lengths, cntGT, perm);
  k_hist2<<<1, 256, 0, stream>>>(cid, cidoff);
  k_scatter2<<<64, 64, 0, stream>>>(cid, cidoff, clist);
  k_prep<<<1024, 256, 0, stream>>>(Wih, Whh, bih, bhh, wcat, wcatX, bias);
  k_bigx<<<16384, 512, 0, stream>>>(hist, wcatX, perm, cntGT, Xbuf);
  k_lstm<<<256, 512, 0, stream>>>(Xbuf, hfin, hx0, hx1, wcat, bias, lengths, perm, ctr);

  k_scores<<<1024, 256, 0, stream>>>(uv, cc, cid, sbuf);
  k_role<<<64, 256, 0, stream>>>(sbuf, cid, hfin, cidoff, clist, rs);
  k_qkv<<<192, 256, 0, stream>>>(rs, Wq, bq, Wk, bk, Wv, bv, qkvg);
  k_mha<<<8, 256, 0, stream>>>(qkvg, attout);
  k_out<<<1, 256, 0, stream>>>(attout, Wo, bo, out);
}